// Round 19
// baseline (27.829 us; speedup 1.0000x reference)
//
#include <hip/hip_runtime.h>

#define NN 128   // modes

typedef float v2f __attribute__((ext_vector_type(2)));   // complex (re, im)

// ---- whole-wave lane shifts via DPP (wave_shl:1 / wave_shr:1), proven R9-R18 ----
__device__ __forceinline__ float wshl1(float x) {   // lane i <- lane i+1
    return __int_as_float(__builtin_amdgcn_update_dpp(
        __float_as_int(x), __float_as_int(x), 0x130, 0xf, 0xf, false));
}
__device__ __forceinline__ float wshr1(float x) {   // lane i <- lane i-1
    return __int_as_float(__builtin_amdgcn_update_dpp(
        __float_as_int(x), __float_as_int(x), 0x138, 0xf, 0xf, false));
}

// i * v: (re,im) -> (-im, re)
__device__ __forceinline__ v2f iswap(v2f v) { return (v2f){-v.y, v.x}; }

// (cos,sin) for the lane's two even rows of one layer: (c0,s0,c1,s1)
__device__ __forceinline__ float4 make_cs(v2f th) {
    float s0, c0, s1, c1;
    __sincosf(th.x, &s0, &c0);
    __sincosf(th.y, &s1, &c1);
    return make_float4(c0, s0, c1, s1);
}

// ---------------- single fused kernel (R18 + addressing/tail cleanup) ----------------
// One wave per column c (128 blocks). Lane l holds rows 4l..4l+3 (4 complex).
// Static 8-deep theta ring; batch-base pointer bump (imm-offset loads, no
// per-step address math); sincos one layer ahead; DPP cross; packed math.
__global__ __launch_bounds__(64) void mesh_fused_kernel(
    const float* __restrict__ theta_in,    // (128,)
    const float* __restrict__ theta_even,  // (255,128)
    const float* __restrict__ theta_out,   // (128,)
    float* __restrict__ out)               // (128,128) f32 = Re(arch)
{
    const int c = blockIdx.x;
    const int l = threadIdx.x;

    const float A  = sqrtf(0.95f * 0.505f);
    const float B  = sqrtf(0.95f * 0.495f);
    const float C2 = sqrtf(0.98f * 0.01f);
    const float S2 = sqrtf(0.98f * 0.99f);

    // branchless corner coeffs: row 0 (l==0, slot v0), row 255 (l==63, slot v3)
    const float ec0 = (l == 0)  ? S2 : C2, es0 = (l == 0)  ? 0.f : S2;
    const float ec3 = (l == 63) ? S2 : C2, es3 = (l == 63) ? 0.f : S2;

    // theta ring: lane l needs theta_even[j*128 + 2l .. 2l+1] = v2f at j*64+l
    const v2f* TL = (const v2f*)theta_even + l;
    v2f t0 = TL[0*64], t1 = TL[1*64], t2 = TL[2*64], t3 = TL[3*64],
        t4 = TL[4*64], t5 = TL[5*64], t6 = TL[6*64], t7 = TL[7*64];

    // init: column c after MMI_IN -> rows 2c: A e^{i th}, 2c+1: iB e^{i th}
    v2f v0 = (v2f){0.f, 0.f}, v1 = v0, v2 = v0, v3 = v0;
    {
        float s, co;
        __sincosf(theta_in[c], &s, &co);
        v2f e0 = (v2f){A * co, A * s};
        v2f e1 = (v2f){-B * s, B * co};
        if (l == (c >> 1)) {
            if (c & 1) { v2 = e0; v3 = e1; }
            else       { v0 = e0; v1 = e1; }
        }
    }

    // rotate-then-mix layer: t = (c0,s0,c1,s1). All packed complex ops.
    auto layer = [&](float4 t) {
        v2f r = t.x * v0 + t.y * iswap(v0);    // e^{i th} * v0
        v2f q = t.z * v2 + t.w * iswap(v2);    // e^{i th'} * v2
        v2f n0 = A * r  + B * iswap(v1);
        v2f n1 = A * v1 + B * iswap(r);
        v2f n2 = A * q  + B * iswap(v3);
        v2f n3 = A * v3 + B * iswap(q);
        v0 = n0; v1 = n1; v2 = n2; v3 = n3;
    };
    auto crossl = [&]() {
        v2f nxt = (v2f){wshl1(v0.x), wshl1(v0.y)};   // lane l+1's v0
        v2f prv = (v2f){wshr1(v3.x), wshr1(v3.y)};   // lane l-1's v3
        v2f m0 = ec0 * v0 + es0 * iswap(prv);
        v2f m3 = ec3 * v3 + es3 * iswap(nxt);
        v2f m1 = C2 * v1 + S2 * iswap(v2);
        v2f m2 = C2 * v2 + S2 * iswap(v1);
        v0 = m0; v1 = m1; v2 = m2; v3 = m3;
    };

    float4 cf = make_cs(t0);   // layer 0 coefficients

    // steady: 30 batches of 8, layers 0..239; loads θ[8..247] — never clamps.
    // TB points at θ[j8+8] for this lane: loads TB[k*64], byte offsets k*512 ≤ 3584
    // fold into the 13-bit imm (single base register, bumped once per batch).
    const v2f* TB = TL + 8 * 64;
    for (int j8 = 0; j8 < 240; j8 += 8) {
        { t0 = TB[0*64]; float4 cfn = make_cs(t1); layer(cf); crossl(); cf = cfn; }
        { t1 = TB[1*64]; float4 cfn = make_cs(t2); layer(cf);           cf = cfn; }
        { t2 = TB[2*64]; float4 cfn = make_cs(t3); layer(cf); crossl(); cf = cfn; }
        { t3 = TB[3*64]; float4 cfn = make_cs(t4); layer(cf);           cf = cfn; }
        { t4 = TB[4*64]; float4 cfn = make_cs(t5); layer(cf); crossl(); cf = cfn; }
        { t5 = TB[5*64]; float4 cfn = make_cs(t6); layer(cf);           cf = cfn; }
        { t6 = TB[6*64]; float4 cfn = make_cs(t7); layer(cf); crossl(); cf = cfn; }
        { t7 = TB[7*64]; float4 cfn = make_cs(t0); layer(cf);           cf = cfn; }
        TB += 8 * 64;
    }
    // tail A: layers 240..247 (ring holds θ[240..247]); load θ[248..254] into t0..t6
    { t0 = TB[0*64]; float4 cfn = make_cs(t1); layer(cf); crossl(); cf = cfn; }   // 240
    { t1 = TB[1*64]; float4 cfn = make_cs(t2); layer(cf);           cf = cfn; }   // 241
    { t2 = TB[2*64]; float4 cfn = make_cs(t3); layer(cf); crossl(); cf = cfn; }   // 242
    { t3 = TB[3*64]; float4 cfn = make_cs(t4); layer(cf);           cf = cfn; }   // 243
    { t4 = TB[4*64]; float4 cfn = make_cs(t5); layer(cf); crossl(); cf = cfn; }   // 244
    { t5 = TB[5*64]; float4 cfn = make_cs(t6); layer(cf);           cf = cfn; }   // 245
    { t6 = TB[6*64]; float4 cfn = make_cs(t7); layer(cf); crossl(); cf = cfn; }   // 246
    {                float4 cfn = make_cs(t0); layer(cf);           cf = cfn; }   // 247
    // tail B: layers 248..253 from t0..t5 (θ[248..253]); fold coef in t6 (θ[254])
    { float4 cfn = make_cs(t1); layer(cf); crossl(); cf = cfn; }   // 248
    { float4 cfn = make_cs(t2); layer(cf);           cf = cfn; }   // 249
    { float4 cfn = make_cs(t3); layer(cf); crossl(); cf = cfn; }   // 250
    { float4 cfn = make_cs(t4); layer(cf);           cf = cfn; }   // 251
    { float4 cfn = make_cs(t5); layer(cf); crossl(); cf = cfn; }   // 252
    { float4 cfn = make_cs(t6); layer(cf);           cf = cfn; }   // 253

    // cf = cs(theta[254]): final diag + MMI_OUT fold -> rows 2l, 2l+1
    v2f r254 = cf.x * v0 + cf.y * iswap(v0);
    v2f q254 = cf.z * v2 + cf.w * iswap(v2);
    v2f o0 = A * r254 + B * iswap(v1);
    v2f o1 = A * q254 + B * iswap(v3);

    // diag(d_out) rotation, keep real part
    v2f tho = ((const v2f*)theta_out)[l];
    float s0, c0, s1, c1;
    __sincosf(tho.x, &s0, &c0);
    __sincosf(tho.y, &s1, &c1);
    out[(2 * l)     * NN + c] = c0 * o0.x - s0 * o0.y;
    out[(2 * l + 1) * NN + c] = c1 * o1.x - s1 * o1.y;
}

extern "C" void kernel_launch(void* const* d_in, const int* in_sizes, int n_in,
                              void* d_out, int out_size, void* d_ws, size_t ws_size,
                              hipStream_t stream) {
    // Identify inputs by SIZE: theta_even is the unique large (32640) array;
    // the two 128-elem arrays keep relative order (theta_in before theta_out).
    int ev = 0;
    for (int i = 0; i < n_in; ++i) if (in_sizes[i] > 1000) ev = i;
    int a = -1, b = -1;
    for (int i = 0; i < n_in; ++i) {
        if (i == ev) continue;
        if (a < 0) a = i; else if (b < 0) b = i;
    }
    const float* th_in  = (const float*)d_in[a];
    const float* th_ev  = (const float*)d_in[ev];
    const float* th_out = (const float*)d_in[b];
    mesh_fused_kernel<<<dim3(NN), dim3(64), 0, stream>>>(
        th_in, th_ev, th_out, (float*)d_out);
}

// Round 20
// 27.501 us; speedup vs baseline: 1.0119x; 1.0119x over previous
//
#include <hip/hip_runtime.h>

#define NN 128   // modes

typedef float v2f __attribute__((ext_vector_type(2)));   // complex (re, im)

// ---- whole-wave lane shifts via DPP (wave_shl:1 / wave_shr:1), proven R9-R19 ----
__device__ __forceinline__ float wshl1(float x) {   // lane i <- lane i+1
    return __int_as_float(__builtin_amdgcn_update_dpp(
        __float_as_int(x), __float_as_int(x), 0x130, 0xf, 0xf, false));
}
__device__ __forceinline__ float wshr1(float x) {   // lane i <- lane i-1
    return __int_as_float(__builtin_amdgcn_update_dpp(
        __float_as_int(x), __float_as_int(x), 0x138, 0xf, 0xf, false));
}

// i * v: (re,im) -> (-im, re)
__device__ __forceinline__ v2f iswap(v2f v) { return (v2f){-v.y, v.x}; }

// (cos,sin) for the lane's two even rows of one layer: (c0,s0,c1,s1)
__device__ __forceinline__ float4 make_cs(v2f th) {
    float s0, c0, s1, c1;
    __sincosf(th.x, &s0, &c0);
    __sincosf(th.y, &s1, &c1);
    return make_float4(c0, s0, c1, s1);
}

// ---------------- single fused kernel (R18 minus coef-rotation pipeline) ----------------
// One wave per column c (128 blocks). Lane l holds rows 4l..4l+3 (4 complex).
// Static 8-deep theta ring, batch-base bump; sincos called AT USE (inputs are
// ring values loaded 8 layers ahead, so scheduler hoists freely — no cf/cfn
// register rotation); DPP cross; packed v2f math.
__global__ __launch_bounds__(64) void mesh_fused_kernel(
    const float* __restrict__ theta_in,    // (128,)
    const float* __restrict__ theta_even,  // (255,128)
    const float* __restrict__ theta_out,   // (128,)
    float* __restrict__ out)               // (128,128) f32 = Re(arch)
{
    const int c = blockIdx.x;
    const int l = threadIdx.x;

    const float A  = sqrtf(0.95f * 0.505f);
    const float B  = sqrtf(0.95f * 0.495f);
    const float C2 = sqrtf(0.98f * 0.01f);
    const float S2 = sqrtf(0.98f * 0.99f);

    // branchless corner coeffs: row 0 (l==0, slot v0), row 255 (l==63, slot v3)
    const float ec0 = (l == 0)  ? S2 : C2, es0 = (l == 0)  ? 0.f : S2;
    const float ec3 = (l == 63) ? S2 : C2, es3 = (l == 63) ? 0.f : S2;

    // theta ring: lane l needs theta_even[j*128 + 2l .. 2l+1] = v2f at j*64+l
    const v2f* TL = (const v2f*)theta_even + l;
    v2f t0 = TL[0*64], t1 = TL[1*64], t2 = TL[2*64], t3 = TL[3*64],
        t4 = TL[4*64], t5 = TL[5*64], t6 = TL[6*64], t7 = TL[7*64];

    // init: column c after MMI_IN -> rows 2c: A e^{i th}, 2c+1: iB e^{i th}
    v2f v0 = (v2f){0.f, 0.f}, v1 = v0, v2 = v0, v3 = v0;
    {
        float s, co;
        __sincosf(theta_in[c], &s, &co);
        v2f e0 = (v2f){A * co, A * s};
        v2f e1 = (v2f){-B * s, B * co};
        if (l == (c >> 1)) {
            if (c & 1) { v2 = e0; v3 = e1; }
            else       { v0 = e0; v1 = e1; }
        }
    }

    // rotate-then-mix layer: t = (c0,s0,c1,s1). All packed complex ops.
    auto layer = [&](float4 t) {
        v2f r = t.x * v0 + t.y * iswap(v0);    // e^{i th} * v0
        v2f q = t.z * v2 + t.w * iswap(v2);    // e^{i th'} * v2
        v2f n0 = A * r  + B * iswap(v1);
        v2f n1 = A * v1 + B * iswap(r);
        v2f n2 = A * q  + B * iswap(v3);
        v2f n3 = A * v3 + B * iswap(q);
        v0 = n0; v1 = n1; v2 = n2; v3 = n3;
    };
    auto crossl = [&]() {
        v2f nxt = (v2f){wshl1(v0.x), wshl1(v0.y)};   // lane l+1's v0
        v2f prv = (v2f){wshr1(v3.x), wshr1(v3.y)};   // lane l-1's v3
        v2f m0 = ec0 * v0 + es0 * iswap(prv);
        v2f m3 = ec3 * v3 + es3 * iswap(nxt);
        v2f m1 = C2 * v1 + S2 * iswap(v2);
        v2f m2 = C2 * v2 + S2 * iswap(v1);
        v0 = m0; v1 = m1; v2 = m2; v3 = m3;
    };

    // steady: 30 batches of 8, layers 0..239; loads θ[8..247] — never clamps.
    // TB = θ[j8+8] lane base; loads at imm offsets k*512 B.
    const v2f* TB = TL + 8 * 64;
    for (int j8 = 0; j8 < 240; j8 += 8) {
        { layer(make_cs(t0)); crossl(); t0 = TB[0*64]; }
        { layer(make_cs(t1));           t1 = TB[1*64]; }
        { layer(make_cs(t2)); crossl(); t2 = TB[2*64]; }
        { layer(make_cs(t3));           t3 = TB[3*64]; }
        { layer(make_cs(t4)); crossl(); t4 = TB[4*64]; }
        { layer(make_cs(t5));           t5 = TB[5*64]; }
        { layer(make_cs(t6)); crossl(); t6 = TB[6*64]; }
        { layer(make_cs(t7));           t7 = TB[7*64]; }
        TB += 8 * 64;
    }
    // ring holds θ[240..247]; tail loads θ[248..254] as scalars-by-slot
    // layers 240..247:
    { layer(make_cs(t0)); crossl(); t0 = TB[0*64]; }   // t0 <- θ[248]
    { layer(make_cs(t1));           t1 = TB[1*64]; }   // t1 <- θ[249]
    { layer(make_cs(t2)); crossl(); t2 = TB[2*64]; }   // t2 <- θ[250]
    { layer(make_cs(t3));           t3 = TB[3*64]; }   // t3 <- θ[251]
    { layer(make_cs(t4)); crossl(); t4 = TB[4*64]; }   // t4 <- θ[252]
    { layer(make_cs(t5));           t5 = TB[5*64]; }   // t5 <- θ[253]
    { layer(make_cs(t6)); crossl(); t6 = TB[6*64]; }   // t6 <- θ[254]
    { layer(make_cs(t7)); }                            // layer 247
    // layers 248..253 (from t0..t5):
    { layer(make_cs(t0)); crossl(); }   // 248
    { layer(make_cs(t1)); }             // 249
    { layer(make_cs(t2)); crossl(); }   // 250
    { layer(make_cs(t3)); }             // 251
    { layer(make_cs(t4)); crossl(); }   // 252
    { layer(make_cs(t5)); }             // 253

    // θ[254] (t6): final diag + MMI_OUT fold -> rows 2l, 2l+1
    float4 cf = make_cs(t6);
    v2f r254 = cf.x * v0 + cf.y * iswap(v0);
    v2f q254 = cf.z * v2 + cf.w * iswap(v2);
    v2f o0 = A * r254 + B * iswap(v1);
    v2f o1 = A * q254 + B * iswap(v3);

    // diag(d_out) rotation, keep real part
    v2f tho = ((const v2f*)theta_out)[l];
    float s0, c0, s1, c1;
    __sincosf(tho.x, &s0, &c0);
    __sincosf(tho.y, &s1, &c1);
    out[(2 * l)     * NN + c] = c0 * o0.x - s0 * o0.y;
    out[(2 * l + 1) * NN + c] = c1 * o1.x - s1 * o1.y;
}

extern "C" void kernel_launch(void* const* d_in, const int* in_sizes, int n_in,
                              void* d_out, int out_size, void* d_ws, size_t ws_size,
                              hipStream_t stream) {
    // Identify inputs by SIZE: theta_even is the unique large (32640) array;
    // the two 128-elem arrays keep relative order (theta_in before theta_out).
    int ev = 0;
    for (int i = 0; i < n_in; ++i) if (in_sizes[i] > 1000) ev = i;
    int a = -1, b = -1;
    for (int i = 0; i < n_in; ++i) {
        if (i == ev) continue;
        if (a < 0) a = i; else if (b < 0) b = i;
    }
    const float* th_in  = (const float*)d_in[a];
    const float* th_ev  = (const float*)d_in[ev];
    const float* th_out = (const float*)d_in[b];
    mesh_fused_kernel<<<dim3(NN), dim3(64), 0, stream>>>(
        th_in, th_ev, th_out, (float*)d_out);
}